// Round 3
// baseline (974.623 us; speedup 1.0000x reference)
//
#include <hip/hip_runtime.h>
#include <math.h>

#define HID 128
#define NUM_G 20
#define EF 4
#define NN 20000
#define NE 640000
#define K1 288            // 280 padded to 9*32
#define A1S 296           // LDS stride (bf16) for edge A-tile
#define A2S 136           // LDS stride for 128-col activation tiles
#define KN1 256           // node GEMM1 K
#define AN1S 264          // LDS stride for node A-tile

typedef __attribute__((ext_vector_type(8))) short short8;
typedef __attribute__((ext_vector_type(4))) short short4v;
typedef __attribute__((ext_vector_type(4))) float floatx4;

__device__ __forceinline__ float silu_f(float v){ return v / (1.0f + __expf(-v)); }
__device__ __forceinline__ float sigm_f(float v){ return 1.0f / (1.0f + __expf(-v)); }
__device__ __forceinline__ unsigned short f2bf(float v){
    unsigned int u = __float_as_uint(v);
    u = (u + 0x7fffu + ((u >> 16) & 1u)) >> 16;
    return (unsigned short)u;
}
__device__ __forceinline__ float bf2f(unsigned short u){
    return __uint_as_float(((unsigned int)u) << 16);
}

__global__ __launch_bounds__(256) void prep_h_kernel(
    const float* __restrict__ h, unsigned short* __restrict__ h_bf)
{
    int i = (blockIdx.x * 256 + threadIdx.x) * 4;
    float4 v = *(const float4*)(h + i);
    short4v o;
    o[0] = (short)f2bf(v.x); o[1] = (short)f2bf(v.y);
    o[2] = (short)f2bf(v.z); o[3] = (short)f2bf(v.w);
    *(short4v*)(h_bf + i) = o;
}

__global__ __launch_bounds__(320) void prep_w_kernel(
    const float* __restrict__ W_e1, const float* __restrict__ W_e2,
    const float* __restrict__ W_x1, const float* __restrict__ W_n1,
    const float* __restrict__ W_n2,
    unsigned short* __restrict__ WT_e1, unsigned short* __restrict__ WT_e2,
    unsigned short* __restrict__ WT_x1, unsigned short* __restrict__ WT_n1,
    unsigned short* __restrict__ WT_n2)
{
    int n = blockIdx.x;
    int t = threadIdx.x;
    if (t < K1)  WT_e1[n*K1  + t] = (t < 280) ? f2bf(W_e1[t*HID + n]) : (unsigned short)0;
    if (t < KN1) WT_n1[n*KN1 + t] = f2bf(W_n1[t*HID + n]);
    if (t < HID) {
        WT_e2[n*HID + t] = f2bf(W_e2[t*HID + n]);
        WT_x1[n*HID + t] = f2bf(W_x1[t*HID + n]);
        WT_n2[n*HID + t] = f2bf(W_n2[t*HID + n]);
    }
}

// ---- counting sort of edges by dst ----
__global__ __launch_bounds__(256) void hist_kernel(
    const int* __restrict__ edge_index, int* __restrict__ counts)
{
    int e = blockIdx.x * 256 + threadIdx.x;
    atomicAdd(&counts[edge_index[NE + e]], 1);
}

__global__ __launch_bounds__(256) void scan_kernel(
    const int* __restrict__ counts, int* __restrict__ cursor)
{
    __shared__ int part[256];
    const int t = threadIdx.x;
    const int CH = (NN + 255) / 256;   // 79
    int base = t * CH;
    int s = 0;
    for (int i = 0; i < CH; ++i) { int idx = base + i; if (idx < NN) s += counts[idx]; }
    part[t] = s; __syncthreads();
    for (int off = 1; off < 256; off <<= 1) {
        int v = (t >= off) ? part[t - off] : 0;
        __syncthreads();
        part[t] += v;
        __syncthreads();
    }
    int run = (t == 0) ? 0 : part[t - 1];
    for (int i = 0; i < CH; ++i) {
        int idx = base + i;
        if (idx < NN) { cursor[idx] = run; run += counts[idx]; }
    }
}

__global__ __launch_bounds__(256) void scatter_kernel(
    const int* __restrict__ edge_index, int* __restrict__ cursor,
    int* __restrict__ order)
{
    int e = blockIdx.x * 256 + threadIdx.x;
    int d = edge_index[NE + e];
    int pos = atomicAdd(&cursor[d], 1);
    order[pos] = e;
}

// ---- edge kernel: 64 sorted edges/block, 256 threads = 4 waves ----
__global__ __launch_bounds__(256) void egnn_edge_mfma(
    const float* __restrict__ x, const float* __restrict__ edge_attr,
    const int* __restrict__ edge_index, const int* __restrict__ order,
    const unsigned short* __restrict__ h_bf,
    const unsigned short* __restrict__ WT_e1,
    const unsigned short* __restrict__ WT_e2,
    const unsigned short* __restrict__ WT_x1,
    const float* __restrict__ b_e1, const float* __restrict__ b_e2,
    const float* __restrict__ W_g,  const float* __restrict__ b_g,
    const float* __restrict__ b_x1, const float* __restrict__ W_x2,
    float* __restrict__ agg, float* __restrict__ dxv)
{
    __shared__ __align__(16) unsigned short A1[64*A1S];  // m_in tile
    __shared__ __align__(16) unsigned short A2[64*A2S];  // m1
    __shared__ __align__(16) unsigned short A3[64*A2S];  // m2 (bf16)
    __shared__ int   s_eid[64];
    __shared__ int   s_dst[66];     // [64]=-1 sentinel slot
    __shared__ int   s_src[64];
    __shared__ float s_rel[64*3];
    __shared__ float s_r[64];
    __shared__ float s_g[64];
    __shared__ float s_vec[64*3];

    const int tid  = threadIdx.x;
    const int lane = tid & 63;
    const int wave = tid >> 6;
    const int quad = lane >> 4;
    const int l15  = lane & 15;
    const int e0   = blockIdx.x * 64;

    float be1[8], be2[8], bx1[8], wg[8], wx2[8];
    #pragma unroll
    for (int t = 0; t < 8; ++t) {
        int c = t*16 + l15;
        be1[t] = b_e1[c]; be2[t] = b_e2[c]; bx1[t] = b_x1[c];
        wg[t]  = W_g[c];  wx2[t] = W_x2[c];
    }
    const float bg0 = b_g[0];

    if (tid < 64) {
        int e = order[e0 + tid];
        s_eid[tid] = e;
        int s = edge_index[e];
        int d = edge_index[NE + e];
        s_src[tid] = s; s_dst[tid] = d;
        float rx = x[d*3+0] - x[s*3+0];
        float ry = x[d*3+1] - x[s*3+1];
        float rz = x[d*3+2] - x[s*3+2];
        float r  = sqrtf(rx*rx + ry*ry + rz*rz + 1e-8f);
        s_rel[tid*3+0] = rx; s_rel[tid*3+1] = ry; s_rel[tid*3+2] = rz;
        s_r[tid] = r;
    }
    if (tid == 64) s_dst[64] = -1;
    __syncthreads();

    // gather h rows (cols 0..255)
    #pragma unroll
    for (int jj = 0; jj < 8; ++jj) {
        int job  = tid + jj*256;
        int e    = job >> 5;
        int half = (job >> 4) & 1;
        int c16  = job & 15;
        int node = half ? s_src[e] : s_dst[e];
        short8 v = *(const short8*)(h_bf + (size_t)node*HID + c16*8);
        *(short8*)(&A1[e*A1S + half*HID + c16*8]) = v;
    }
    // cols 256..287: RBF | edge_attr | pad
    const float step  = 10.0f / 19.0f;
    const float coeff = -0.5f / (step*step);
    #pragma unroll
    for (int jj = 0; jj < 8; ++jj) {
        int job = tid + jj*256;
        int e = job >> 5;
        int j = job & 31;
        unsigned short val;
        if (j < NUM_G) {
            float d = s_r[e] - step*(float)j;
            val = f2bf(__expf(coeff*d*d));
        } else if (j < NUM_G+EF) {
            val = f2bf(edge_attr[(size_t)s_eid[e]*EF + (j-NUM_G)]);
        } else {
            val = 0;
        }
        A1[e*A1S + 256 + j] = val;
    }
    __syncthreads();

    floatx4 acc[8];

    // GEMM1 -> m1 in A2
    #pragma unroll
    for (int t = 0; t < 8; ++t) acc[t] = (floatx4){0.f,0.f,0.f,0.f};
    #pragma unroll
    for (int kc = 0; kc < 9; ++kc) {
        short8 a = *(const short8*)(&A1[(wave*16 + l15)*A1S + kc*32 + quad*8]);
        #pragma unroll
        for (int t = 0; t < 8; ++t) {
            short8 b = *(const short8*)(WT_e1 + (size_t)(t*16+l15)*K1 + kc*32 + quad*8);
            acc[t] = __builtin_amdgcn_mfma_f32_16x16x32_bf16(a, b, acc[t], 0, 0, 0);
        }
    }
    #pragma unroll
    for (int t = 0; t < 8; ++t) {
        int col = t*16 + l15;
        #pragma unroll
        for (int i = 0; i < 4; ++i) {
            int row = wave*16 + quad*4 + i;
            A2[row*A2S + col] = f2bf(silu_f(acc[t][i] + be1[t]));
        }
    }
    __syncthreads();

    // GEMM2 -> m2, gate
    #pragma unroll
    for (int t = 0; t < 8; ++t) acc[t] = (floatx4){0.f,0.f,0.f,0.f};
    #pragma unroll
    for (int kc = 0; kc < 4; ++kc) {
        short8 a = *(const short8*)(&A2[(wave*16 + l15)*A2S + kc*32 + quad*8]);
        #pragma unroll
        for (int t = 0; t < 8; ++t) {
            short8 b = *(const short8*)(WT_e2 + (size_t)(t*16+l15)*HID + kc*32 + quad*8);
            acc[t] = __builtin_amdgcn_mfma_f32_16x16x32_bf16(a, b, acc[t], 0, 0, 0);
        }
    }
    float m2v[8][4];
    float gp[4] = {0.f,0.f,0.f,0.f};
    #pragma unroll
    for (int t = 0; t < 8; ++t)
        #pragma unroll
        for (int i = 0; i < 4; ++i) {
            float m2 = silu_f(acc[t][i] + be2[t]);
            m2v[t][i] = m2;
            gp[i] += m2 * wg[t];
        }
    #pragma unroll
    for (int i = 0; i < 4; ++i) {
        gp[i] += __shfl_xor(gp[i], 1);
        gp[i] += __shfl_xor(gp[i], 2);
        gp[i] += __shfl_xor(gp[i], 4);
        gp[i] += __shfl_xor(gp[i], 8);
        gp[i] = sigm_f(gp[i] + bg0);
    }
    if (l15 == 0) {
        #pragma unroll
        for (int i = 0; i < 4; ++i) s_g[wave*16 + quad*4 + i] = gp[i];
    }
    #pragma unroll
    for (int t = 0; t < 8; ++t) {
        int col = t*16 + l15;
        #pragma unroll
        for (int i = 0; i < 4; ++i) {
            int row = wave*16 + quad*4 + i;
            A3[row*A2S + col] = f2bf(m2v[t][i]);
        }
    }
    __syncthreads();

    // segmented reduce of msg = bf(m2)*g by dst -> few atomics
    {
        int col  = tid & 127;
        int r0   = (tid >> 7) * 32;
        float a  = 0.f;
        #pragma unroll 8
        for (int r = r0; r < r0 + 32; ++r) {
            a += bf2f(A3[r*A2S + col]) * s_g[r];
            bool flush = (r == r0 + 31) || (s_dst[r + 1] != s_dst[r]);
            if (flush) {
                atomicAdd(&agg[(size_t)s_dst[r]*HID + col], a);
                a = 0.f;
            }
        }
    }

    // GEMM3: coord head
    #pragma unroll
    for (int t = 0; t < 8; ++t) acc[t] = (floatx4){0.f,0.f,0.f,0.f};
    #pragma unroll
    for (int kc = 0; kc < 4; ++kc) {
        short8 a = *(const short8*)(&A3[(wave*16 + l15)*A2S + kc*32 + quad*8]);
        #pragma unroll
        for (int t = 0; t < 8; ++t) {
            short8 b = *(const short8*)(WT_x1 + (size_t)(t*16+l15)*HID + kc*32 + quad*8);
            acc[t] = __builtin_amdgcn_mfma_f32_16x16x32_bf16(a, b, acc[t], 0, 0, 0);
        }
    }
    float cp[4] = {0.f,0.f,0.f,0.f};
    #pragma unroll
    for (int t = 0; t < 8; ++t)
        #pragma unroll
        for (int i = 0; i < 4; ++i)
            cp[i] += silu_f(acc[t][i] + bx1[t]) * wx2[t];
    #pragma unroll
    for (int i = 0; i < 4; ++i) {
        cp[i] += __shfl_xor(cp[i], 1);
        cp[i] += __shfl_xor(cp[i], 2);
        cp[i] += __shfl_xor(cp[i], 4);
        cp[i] += __shfl_xor(cp[i], 8);
        cp[i] = tanhf(cp[i]);
    }
    if (l15 < 3) {
        #pragma unroll
        for (int i = 0; i < 4; ++i) {
            int row = wave*16 + quad*4 + i;
            s_vec[row*3 + l15] = s_rel[row*3 + l15] / (s_r[row] + 1.0f) * cp[i];
        }
    }
    __syncthreads();

    // segmented reduce of vec by dst
    if (tid < 3) {
        float a = 0.f;
        for (int r = 0; r < 64; ++r) {
            a += s_vec[r*3 + tid];
            bool flush = (r == 63) || (s_dst[r + 1] != s_dst[r]);
            if (flush) {
                atomicAdd(&dxv[(size_t)s_dst[r]*3 + tid], a);
                a = 0.f;
            }
        }
    }
}

// ---- node kernel: 64 nodes/block ----
__global__ __launch_bounds__(256) void egnn_node_mfma(
    const float* __restrict__ h, const float* __restrict__ x,
    const int* __restrict__ mask,
    const unsigned short* __restrict__ h_bf,
    const float* __restrict__ agg, const float* __restrict__ dxv,
    const unsigned short* __restrict__ WT_n1, const float* __restrict__ b_n1,
    const unsigned short* __restrict__ WT_n2, const float* __restrict__ b_n2,
    float* __restrict__ h_out, float* __restrict__ x_out)
{
    __shared__ __align__(16) unsigned short A1[64*AN1S];
    __shared__ __align__(16) unsigned short A2[64*A2S];

    const int tid  = threadIdx.x;
    const int lane = tid & 63;
    const int wave = tid >> 6;
    const int quad = lane >> 4;
    const int l15  = lane & 15;
    const int n0   = blockIdx.x * 64;

    if (tid < 192) {
        int r = tid / 3, c = tid % 3;
        int n = n0 + r;
        if (n < NN) x_out[n*3 + c] = x[n*3 + c] + dxv[n*3 + c] * (float)mask[n];
    }

    float bn1[8], bn2[8];
    #pragma unroll
    for (int t = 0; t < 8; ++t) {
        int c = t*16 + l15;
        bn1[t] = b_n1[c]; bn2[t] = b_n2[c];
    }

    #pragma unroll
    for (int jj = 0; jj < 8; ++jj) {
        int job = tid + jj*256;
        int r = job >> 5;
        int c4 = job & 31;
        int n = n0 + r;
        short4v o;
        if (n < NN) {
            float4 v = *((const float4*)(agg + (size_t)n*HID) + c4);
            o[0] = (short)f2bf(v.x); o[1] = (short)f2bf(v.y);
            o[2] = (short)f2bf(v.z); o[3] = (short)f2bf(v.w);
        } else { o[0]=o[1]=o[2]=o[3]=0; }
        *(short4v*)(&A1[r*AN1S + c4*4]) = o;
    }
    #pragma unroll
    for (int jj = 0; jj < 4; ++jj) {
        int job = tid + jj*256;
        int r = job >> 4;
        int c16 = job & 15;
        int n = n0 + r;
        short8 v;
        if (n < NN) v = *(const short8*)(h_bf + (size_t)n*HID + c16*8);
        else        v = (short8){0,0,0,0,0,0,0,0};
        *(short8*)(&A1[r*AN1S + HID + c16*8]) = v;
    }
    __syncthreads();

    floatx4 acc[8];
    #pragma unroll
    for (int t = 0; t < 8; ++t) acc[t] = (floatx4){0.f,0.f,0.f,0.f};
    #pragma unroll
    for (int kc = 0; kc < 8; ++kc) {
        short8 a = *(const short8*)(&A1[(wave*16 + l15)*AN1S + kc*32 + quad*8]);
        #pragma unroll
        for (int t = 0; t < 8; ++t) {
            short8 b = *(const short8*)(WT_n1 + (size_t)(t*16+l15)*KN1 + kc*32 + quad*8);
            acc[t] = __builtin_amdgcn_mfma_f32_16x16x32_bf16(a, b, acc[t], 0, 0, 0);
        }
    }
    #pragma unroll
    for (int t = 0; t < 8; ++t) {
        int col = t*16 + l15;
        #pragma unroll
        for (int i = 0; i < 4; ++i) {
            int row = wave*16 + quad*4 + i;
            A2[row*A2S + col] = f2bf(silu_f(acc[t][i] + bn1[t]));
        }
    }
    __syncthreads();

    #pragma unroll
    for (int t = 0; t < 8; ++t) acc[t] = (floatx4){0.f,0.f,0.f,0.f};
    #pragma unroll
    for (int kc = 0; kc < 4; ++kc) {
        short8 a = *(const short8*)(&A2[(wave*16 + l15)*A2S + kc*32 + quad*8]);
        #pragma unroll
        for (int t = 0; t < 8; ++t) {
            short8 b = *(const short8*)(WT_n2 + (size_t)(t*16+l15)*HID + kc*32 + quad*8);
            acc[t] = __builtin_amdgcn_mfma_f32_16x16x32_bf16(a, b, acc[t], 0, 0, 0);
        }
    }
    #pragma unroll
    for (int t = 0; t < 8; ++t) {
        int col = t*16 + l15;
        #pragma unroll
        for (int i = 0; i < 4; ++i) {
            int row = wave*16 + quad*4 + i;
            int n = n0 + row;
            if (n < NN)
                h_out[(size_t)n*HID + col] = h[(size_t)n*HID + col] + acc[t][i] + bn2[t];
        }
    }
}

extern "C" void kernel_launch(void* const* d_in, const int* in_sizes, int n_in,
                              void* d_out, int out_size, void* d_ws, size_t ws_size,
                              hipStream_t stream) {
    const float* h          = (const float*)d_in[0];
    const float* x          = (const float*)d_in[1];
    const float* edge_attr  = (const float*)d_in[2];
    const int*   edge_index = (const int*)  d_in[3];
    const int*   mask       = (const int*)  d_in[4];
    const float* W_e1 = (const float*)d_in[5];
    const float* b_e1 = (const float*)d_in[6];
    const float* W_e2 = (const float*)d_in[7];
    const float* b_e2 = (const float*)d_in[8];
    const float* W_g  = (const float*)d_in[9];
    const float* b_g  = (const float*)d_in[10];
    const float* W_n1 = (const float*)d_in[11];
    const float* b_n1 = (const float*)d_in[12];
    const float* W_n2 = (const float*)d_in[13];
    const float* b_n2 = (const float*)d_in[14];
    const float* W_x1 = (const float*)d_in[15];
    const float* b_x1 = (const float*)d_in[16];
    const float* W_x2 = (const float*)d_in[17];

    char* ws = (char*)d_ws;
    float* agg = (float*)ws;                       ws += (size_t)NN*HID*4;
    float* dxv = (float*)ws;                       ws += (size_t)NN*3*4;
    int*   counts = (int*)ws;                      ws += (size_t)NN*4;
    int*   cursor = (int*)ws;                      ws += (size_t)NN*4;
    int*   order  = (int*)ws;                      ws += (size_t)NE*4;
    unsigned short* h_bf  = (unsigned short*)ws;   ws += (size_t)NN*HID*2;
    unsigned short* WT_e1 = (unsigned short*)ws;   ws += (size_t)HID*K1*2;
    unsigned short* WT_e2 = (unsigned short*)ws;   ws += (size_t)HID*HID*2;
    unsigned short* WT_x1 = (unsigned short*)ws;   ws += (size_t)HID*HID*2;
    unsigned short* WT_n1 = (unsigned short*)ws;   ws += (size_t)HID*KN1*2;
    unsigned short* WT_n2 = (unsigned short*)ws;   ws += (size_t)HID*HID*2;

    hipMemsetAsync(agg, 0, ((size_t)NN*HID + (size_t)NN*3)*sizeof(float), stream);
    hipMemsetAsync(counts, 0, (size_t)NN*sizeof(int), stream);

    prep_h_kernel<<<2500, 256, 0, stream>>>(h, h_bf);
    prep_w_kernel<<<128, 320, 0, stream>>>(W_e1, W_e2, W_x1, W_n1, W_n2,
                                           WT_e1, WT_e2, WT_x1, WT_n1, WT_n2);
    hist_kernel<<<NE/256, 256, 0, stream>>>(edge_index, counts);
    scan_kernel<<<1, 256, 0, stream>>>(counts, cursor);
    scatter_kernel<<<NE/256, 256, 0, stream>>>(edge_index, cursor, order);

    egnn_edge_mfma<<<NE/64, 256, 0, stream>>>(
        x, edge_attr, edge_index, order, h_bf, WT_e1, WT_e2, WT_x1,
        b_e1, b_e2, W_g, b_g, b_x1, W_x2, agg, dxv);

    float* h_out = (float*)d_out;
    float* x_out = h_out + (size_t)NN*HID;

    egnn_node_mfma<<<(NN + 63)/64, 256, 0, stream>>>(
        h, x, mask, h_bf, agg, dxv, WT_n1, b_n1, WT_n2, b_n2, h_out, x_out);
}

// Round 4
// 728.529 us; speedup vs baseline: 1.3378x; 1.3378x over previous
//
#include <hip/hip_runtime.h>
#include <math.h>

#define HID 128
#define NUM_G 20
#define EF 4
#define NN 20000
#define NE 640000
#define K1 288            // 280 padded to 9*32
#define KN1 256           // node GEMM1 K
#define TS 136            // transpose buffer stride (bf16): 272B rows -> 2-way LDS conflict only
#define RBFS 40           // RBF block stride: 80B rows -> 2-way

typedef __attribute__((ext_vector_type(8))) short short8;
typedef __attribute__((ext_vector_type(4))) short short4v;
typedef __attribute__((ext_vector_type(4))) float floatx4;

__device__ __forceinline__ float silu_f(float v){ return v / (1.0f + __expf(-v)); }
__device__ __forceinline__ float sigm_f(float v){ return 1.0f / (1.0f + __expf(-v)); }
__device__ __forceinline__ unsigned short f2bf(float v){
    unsigned int u = __float_as_uint(v);
    u = (u + 0x7fffu + ((u >> 16) & 1u)) >> 16;
    return (unsigned short)u;
}
__device__ __forceinline__ float bf2f(unsigned int u){
    return __uint_as_float(u << 16);
}

__global__ __launch_bounds__(256) void prep_h_kernel(
    const float* __restrict__ h, unsigned short* __restrict__ h_bf)
{
    int i = (blockIdx.x * 256 + threadIdx.x) * 4;
    float4 v = *(const float4*)(h + i);
    short4v o;
    o[0] = (short)f2bf(v.x); o[1] = (short)f2bf(v.y);
    o[2] = (short)f2bf(v.z); o[3] = (short)f2bf(v.w);
    *(short4v*)(h_bf + i) = o;
}

__global__ __launch_bounds__(320) void prep_w_kernel(
    const float* __restrict__ W_e1, const float* __restrict__ W_e2,
    const float* __restrict__ W_x1, const float* __restrict__ W_n1,
    const float* __restrict__ W_n2,
    unsigned short* __restrict__ WT_e1, unsigned short* __restrict__ WT_e2,
    unsigned short* __restrict__ WT_x1, unsigned short* __restrict__ WT_n1,
    unsigned short* __restrict__ WT_n2)
{
    int n = blockIdx.x;
    int t = threadIdx.x;
    if (t < K1)  WT_e1[n*K1  + t] = (t < 280) ? f2bf(W_e1[t*HID + n]) : (unsigned short)0;
    if (t < KN1) WT_n1[n*KN1 + t] = f2bf(W_n1[t*HID + n]);
    if (t < HID) {
        WT_e2[n*HID + t] = f2bf(W_e2[t*HID + n]);
        WT_x1[n*HID + t] = f2bf(W_x1[t*HID + n]);
        WT_n2[n*HID + t] = f2bf(W_n2[t*HID + n]);
    }
}

// ---- counting sort of edges by dst ----
__global__ __launch_bounds__(256) void hist_kernel(
    const int* __restrict__ edge_index, int* __restrict__ counts)
{
    int e = blockIdx.x * 256 + threadIdx.x;
    atomicAdd(&counts[edge_index[NE + e]], 1);
}

__global__ __launch_bounds__(256) void scan_kernel(
    const int* __restrict__ counts, int* __restrict__ cursor)
{
    __shared__ int part[256];
    const int t = threadIdx.x;
    const int CH = (NN + 255) / 256;
    int base = t * CH;
    int s = 0;
    for (int i = 0; i < CH; ++i) { int idx = base + i; if (idx < NN) s += counts[idx]; }
    part[t] = s; __syncthreads();
    for (int off = 1; off < 256; off <<= 1) {
        int v = (t >= off) ? part[t - off] : 0;
        __syncthreads();
        part[t] += v;
        __syncthreads();
    }
    int run = (t == 0) ? 0 : part[t - 1];
    for (int i = 0; i < CH; ++i) {
        int idx = base + i;
        if (idx < NN) { cursor[idx] = run; run += counts[idx]; }
    }
}

__global__ __launch_bounds__(256) void scatter_kernel(
    const int* __restrict__ edge_index, int* __restrict__ cursor,
    int* __restrict__ order)
{
    int e = blockIdx.x * 256 + threadIdx.x;
    int d = edge_index[NE + e];
    int pos = atomicAdd(&cursor[d], 1);
    order[pos] = e;
}

// ---- edge kernel: ONE WAVE per block, 16 sorted edges per wave, no __syncthreads ----
__global__ __launch_bounds__(64, 4) void egnn_edge_mfma(
    const float* __restrict__ x, const float* __restrict__ edge_attr,
    const int* __restrict__ edge_index, const int* __restrict__ order,
    const unsigned short* __restrict__ h_bf,
    const unsigned short* __restrict__ WT_e1,
    const unsigned short* __restrict__ WT_e2,
    const unsigned short* __restrict__ WT_x1,
    const float* __restrict__ b_e1, const float* __restrict__ b_e2,
    const float* __restrict__ W_g,  const float* __restrict__ b_g,
    const float* __restrict__ b_x1, const float* __restrict__ W_x2,
    float* __restrict__ agg, float* __restrict__ dxv)
{
    __shared__ __align__(16) unsigned short T[16*TS];      // m1, then m2
    __shared__ __align__(16) unsigned short RBF[16*RBFS];  // rbf|attr|zeros (32 used cols)
    __shared__ int   s_eid[16];
    __shared__ int   s_dst[17];    // [16] = -1 sentinel
    __shared__ int   s_src[16];
    __shared__ float s_rel[48];
    __shared__ float s_r[16];
    __shared__ float s_g[16];
    __shared__ float s_vec[48];

    const int lane = threadIdx.x;   // 0..63
    const int quad = lane >> 4;
    const int l15  = lane & 15;
    const int e0   = blockIdx.x * 16;

    // --- meta: lanes 0..15 own one edge each ---
    if (lane < 16) {
        int e = order[e0 + lane];
        s_eid[lane] = e;
        int s = edge_index[e];
        int d = edge_index[NE + e];
        s_src[lane] = s; s_dst[lane] = d;
        float rx = x[d*3+0] - x[s*3+0];
        float ry = x[d*3+1] - x[s*3+1];
        float rz = x[d*3+2] - x[s*3+2];
        float r  = sqrtf(rx*rx + ry*ry + rz*rz + 1e-8f);
        s_rel[lane*3+0] = rx; s_rel[lane*3+1] = ry; s_rel[lane*3+2] = rz;
        s_r[lane] = r;
    }
    if (lane == 16) s_dst[16] = -1;
    __builtin_amdgcn_wave_barrier();

    // --- RBF block fill: 16 rows x 40 cols (col j*4+quad) ---
    {
        const float step  = 10.0f / 19.0f;
        const float coeff = -0.5f / (step*step);
        float rr = s_r[l15];
        int eid = s_eid[l15];
        #pragma unroll
        for (int j = 0; j < 10; ++j) {
            int col = quad + j*4;
            unsigned short v;
            if (col < NUM_G) {
                float d = rr - step*(float)col;
                v = f2bf(__expf(coeff*d*d));
            } else if (col < NUM_G+EF) {
                v = f2bf(edge_attr[(size_t)eid*EF + (col-NUM_G)]);
            } else v = 0;
            RBF[l15*RBFS + col] = v;
        }
    }
    __builtin_amdgcn_wave_barrier();

    // --- GEMM1 A-fragments: direct global gather, no LDS staging ---
    const int nd = s_dst[l15], ns = s_src[l15];
    const unsigned short* hd = h_bf + (size_t)nd*HID + quad*8;
    const unsigned short* hs = h_bf + (size_t)ns*HID + quad*8;
    short8 a1[9];
    #pragma unroll
    for (int kc = 0; kc < 4; ++kc) a1[kc]   = *(const short8*)(hd + kc*32);
    #pragma unroll
    for (int kc = 0; kc < 4; ++kc) a1[4+kc] = *(const short8*)(hs + kc*32);
    a1[8] = *(const short8*)(&RBF[l15*RBFS + quad*8]);

    floatx4 acc[8];
    #pragma unroll
    for (int t = 0; t < 8; ++t) acc[t] = (floatx4){0.f,0.f,0.f,0.f};
    #pragma unroll
    for (int kc = 0; kc < 9; ++kc) {
        #pragma unroll
        for (int t = 0; t < 8; ++t) {
            short8 b = *(const short8*)(WT_e1 + (size_t)(t*16+l15)*K1 + kc*32 + quad*8);
            acc[t] = __builtin_amdgcn_mfma_f32_16x16x32_bf16(a1[kc], b, acc[t], 0, 0, 0);
        }
    }
    // epilogue 1: m1 = silu(acc + b_e1) -> T
    #pragma unroll
    for (int t = 0; t < 8; ++t) {
        int col = t*16 + l15;
        float bv = b_e1[col];
        #pragma unroll
        for (int i = 0; i < 4; ++i)
            T[(quad*4+i)*TS + col] = f2bf(silu_f(acc[t][i] + bv));
    }
    __builtin_amdgcn_wave_barrier();

    // --- GEMM2: m2 = silu(m1 @ W_e2 + b), gate ---
    short8 a2[4];
    #pragma unroll
    for (int kc = 0; kc < 4; ++kc)
        a2[kc] = *(const short8*)(&T[l15*TS + kc*32 + quad*8]);
    #pragma unroll
    for (int t = 0; t < 8; ++t) acc[t] = (floatx4){0.f,0.f,0.f,0.f};
    #pragma unroll
    for (int kc = 0; kc < 4; ++kc) {
        #pragma unroll
        for (int t = 0; t < 8; ++t) {
            short8 b = *(const short8*)(WT_e2 + (size_t)(t*16+l15)*HID + kc*32 + quad*8);
            acc[t] = __builtin_amdgcn_mfma_f32_16x16x32_bf16(a2[kc], b, acc[t], 0, 0, 0);
        }
    }
    float gp[4] = {0.f,0.f,0.f,0.f};
    #pragma unroll
    for (int t = 0; t < 8; ++t) {
        int col = t*16 + l15;
        float bv = b_e2[col];
        float wgv = W_g[col];
        #pragma unroll
        for (int i = 0; i < 4; ++i) {
            float m2 = silu_f(acc[t][i] + bv);
            gp[i] += m2 * wgv;
            T[(quad*4+i)*TS + col] = f2bf(m2);     // overwrite m1 with m2
        }
    }
    {
        const float bg0 = b_g[0];
        #pragma unroll
        for (int i = 0; i < 4; ++i) {
            gp[i] += __shfl_xor(gp[i], 1);
            gp[i] += __shfl_xor(gp[i], 2);
            gp[i] += __shfl_xor(gp[i], 4);
            gp[i] += __shfl_xor(gp[i], 8);
            gp[i] = sigm_f(gp[i] + bg0);
        }
        if (l15 == 0) {
            #pragma unroll
            for (int i = 0; i < 4; ++i) s_g[quad*4 + i] = gp[i];
        }
    }
    __builtin_amdgcn_wave_barrier();

    // --- GEMM3 A-frags (m2 from T) ---
    short8 a3[4];
    #pragma unroll
    for (int kc = 0; kc < 4; ++kc)
        a3[kc] = *(const short8*)(&T[l15*TS + kc*32 + quad*8]);

    // --- segmented msg reduce: lane owns cols 2*lane, 2*lane+1 ---
    {
        float am0 = 0.f, am1 = 0.f;
        #pragma unroll
        for (int r = 0; r < 16; ++r) {
            unsigned int pv = *(const unsigned int*)(&T[r*TS + lane*2]);
            float gr = s_g[r];
            am0 += bf2f(pv & 0xffffu) * gr;
            am1 += bf2f(pv >> 16) * gr;
            int dr = s_dst[r];
            if (dr != s_dst[r+1]) {
                atomicAdd(&agg[(size_t)dr*HID + lane*2],     am0);
                atomicAdd(&agg[(size_t)dr*HID + lane*2 + 1], am1);
                am0 = 0.f; am1 = 0.f;
            }
        }
    }

    // --- GEMM3: coord head ---
    #pragma unroll
    for (int t = 0; t < 8; ++t) acc[t] = (floatx4){0.f,0.f,0.f,0.f};
    #pragma unroll
    for (int kc = 0; kc < 4; ++kc) {
        #pragma unroll
        for (int t = 0; t < 8; ++t) {
            short8 b = *(const short8*)(WT_x1 + (size_t)(t*16+l15)*HID + kc*32 + quad*8);
            acc[t] = __builtin_amdgcn_mfma_f32_16x16x32_bf16(a3[kc], b, acc[t], 0, 0, 0);
        }
    }
    float cp[4] = {0.f,0.f,0.f,0.f};
    #pragma unroll
    for (int t = 0; t < 8; ++t) {
        int col = t*16 + l15;
        float bv = b_x1[col];
        float wx = W_x2[col];
        #pragma unroll
        for (int i = 0; i < 4; ++i)
            cp[i] += silu_f(acc[t][i] + bv) * wx;
    }
    #pragma unroll
    for (int i = 0; i < 4; ++i) {
        cp[i] += __shfl_xor(cp[i], 1);
        cp[i] += __shfl_xor(cp[i], 2);
        cp[i] += __shfl_xor(cp[i], 4);
        cp[i] += __shfl_xor(cp[i], 8);
        cp[i] = tanhf(cp[i]);
    }
    if (l15 < 3) {
        #pragma unroll
        for (int i = 0; i < 4; ++i) {
            int row = quad*4 + i;
            s_vec[row*3 + l15] = s_rel[row*3 + l15] / (s_r[row] + 1.0f) * cp[i];
        }
    }
    __builtin_amdgcn_wave_barrier();

    if (lane < 3) {
        float a = 0.f;
        #pragma unroll
        for (int r = 0; r < 16; ++r) {
            a += s_vec[r*3 + lane];
            int dr = s_dst[r];
            if (dr != s_dst[r+1]) {
                atomicAdd(&dxv[(size_t)dr*3 + lane], a);
                a = 0.f;
            }
        }
    }
}

// ---- node kernel: ONE WAVE per block, 16 nodes, no __syncthreads ----
__global__ __launch_bounds__(64, 4) void egnn_node_mfma(
    const float* __restrict__ h, const float* __restrict__ x,
    const int* __restrict__ mask,
    const unsigned short* __restrict__ h_bf,
    const float* __restrict__ agg, const float* __restrict__ dxv,
    const unsigned short* __restrict__ WT_n1, const float* __restrict__ b_n1,
    const unsigned short* __restrict__ WT_n2, const float* __restrict__ b_n2,
    float* __restrict__ h_out, float* __restrict__ x_out)
{
    __shared__ __align__(16) unsigned short T[16*TS];

    const int lane = threadIdx.x;
    const int quad = lane >> 4;
    const int l15  = lane & 15;
    const int n0   = blockIdx.x * 16;     // NN = 1250*16 exactly

    if (lane < 48) {
        int r = lane / 3, c = lane % 3;
        int n = n0 + r;
        x_out[n*3 + c] = x[n*3 + c] + dxv[n*3 + c] * (float)mask[n];
    }

    // A-frags: cols 0..127 from agg (f32 -> bf16), 128..255 from h_bf
    const int node = n0 + l15;
    short8 a1[8];
    #pragma unroll
    for (int kc = 0; kc < 4; ++kc) {
        const float* p = agg + (size_t)node*HID + kc*32 + quad*8;
        float4 f0 = *(const float4*)(p);
        float4 f1 = *(const float4*)(p + 4);
        short8 v;
        v[0]=(short)f2bf(f0.x); v[1]=(short)f2bf(f0.y); v[2]=(short)f2bf(f0.z); v[3]=(short)f2bf(f0.w);
        v[4]=(short)f2bf(f1.x); v[5]=(short)f2bf(f1.y); v[6]=(short)f2bf(f1.z); v[7]=(short)f2bf(f1.w);
        a1[kc] = v;
    }
    #pragma unroll
    for (int kc = 0; kc < 4; ++kc)
        a1[4+kc] = *(const short8*)(h_bf + (size_t)node*HID + kc*32 + quad*8);

    floatx4 acc[8];
    #pragma unroll
    for (int t = 0; t < 8; ++t) acc[t] = (floatx4){0.f,0.f,0.f,0.f};
    #pragma unroll
    for (int kc = 0; kc < 8; ++kc) {
        #pragma unroll
        for (int t = 0; t < 8; ++t) {
            short8 b = *(const short8*)(WT_n1 + (size_t)(t*16+l15)*KN1 + kc*32 + quad*8);
            acc[t] = __builtin_amdgcn_mfma_f32_16x16x32_bf16(a1[kc], b, acc[t], 0, 0, 0);
        }
    }
    #pragma unroll
    for (int t = 0; t < 8; ++t) {
        int col = t*16 + l15;
        float bv = b_n1[col];
        #pragma unroll
        for (int i = 0; i < 4; ++i)
            T[(quad*4+i)*TS + col] = f2bf(silu_f(acc[t][i] + bv));
    }
    __builtin_amdgcn_wave_barrier();

    short8 a2[4];
    #pragma unroll
    for (int kc = 0; kc < 4; ++kc)
        a2[kc] = *(const short8*)(&T[l15*TS + kc*32 + quad*8]);
    #pragma unroll
    for (int t = 0; t < 8; ++t) acc[t] = (floatx4){0.f,0.f,0.f,0.f};
    #pragma unroll
    for (int kc = 0; kc < 4; ++kc) {
        #pragma unroll
        for (int t = 0; t < 8; ++t) {
            short8 b = *(const short8*)(WT_n2 + (size_t)(t*16+l15)*HID + kc*32 + quad*8);
            acc[t] = __builtin_amdgcn_mfma_f32_16x16x32_bf16(a2[kc], b, acc[t], 0, 0, 0);
        }
    }
    #pragma unroll
    for (int t = 0; t < 8; ++t) {
        int col = t*16 + l15;
        float bv = b_n2[col];
        #pragma unroll
        for (int i = 0; i < 4; ++i) {
            int n = n0 + quad*4 + i;
            h_out[(size_t)n*HID + col] = h[(size_t)n*HID + col] + acc[t][i] + bv;
        }
    }
}

extern "C" void kernel_launch(void* const* d_in, const int* in_sizes, int n_in,
                              void* d_out, int out_size, void* d_ws, size_t ws_size,
                              hipStream_t stream) {
    const float* h          = (const float*)d_in[0];
    const float* x          = (const float*)d_in[1];
    const float* edge_attr  = (const float*)d_in[2];
    const int*   edge_index = (const int*)  d_in[3];
    const int*   mask       = (const int*)  d_in[4];
    const float* W_e1 = (const float*)d_in[5];
    const float* b_e1 = (const float*)d_in[6];
    const float* W_e2 = (const float*)d_in[7];
    const float* b_e2 = (const float*)d_in[8];
    const float* W_g  = (const float*)d_in[9];
    const float* b_g  = (const float*)d_in[10];
    const float* W_n1 = (const float*)d_in[11];
    const float* b_n1 = (const float*)d_in[12];
    const float* W_n2 = (const float*)d_in[13];
    const float* b_n2 = (const float*)d_in[14];
    const float* W_x1 = (const float*)d_in[15];
    const float* b_x1 = (const float*)d_in[16];
    const float* W_x2 = (const float*)d_in[17];

    char* ws = (char*)d_ws;
    float* agg = (float*)ws;                       ws += (size_t)NN*HID*4;
    float* dxv = (float*)ws;                       ws += (size_t)NN*3*4;
    int*   counts = (int*)ws;                      ws += (size_t)NN*4;
    int*   cursor = (int*)ws;                      ws += (size_t)NN*4;
    int*   order  = (int*)ws;                      ws += (size_t)NE*4;
    unsigned short* h_bf  = (unsigned short*)ws;   ws += (size_t)NN*HID*2;
    unsigned short* WT_e1 = (unsigned short*)ws;   ws += (size_t)HID*K1*2;
    unsigned short* WT_e2 = (unsigned short*)ws;   ws += (size_t)HID*HID*2;
    unsigned short* WT_x1 = (unsigned short*)ws;   ws += (size_t)HID*HID*2;
    unsigned short* WT_n1 = (unsigned short*)ws;   ws += (size_t)HID*KN1*2;
    unsigned short* WT_n2 = (unsigned short*)ws;   ws += (size_t)HID*HID*2;

    hipMemsetAsync(agg, 0, ((size_t)NN*HID + (size_t)NN*3)*sizeof(float), stream);
    hipMemsetAsync(counts, 0, (size_t)NN*sizeof(int), stream);

    prep_h_kernel<<<2500, 256, 0, stream>>>(h, h_bf);
    prep_w_kernel<<<128, 320, 0, stream>>>(W_e1, W_e2, W_x1, W_n1, W_n2,
                                           WT_e1, WT_e2, WT_x1, WT_n1, WT_n2);
    hist_kernel<<<NE/256, 256, 0, stream>>>(edge_index, counts);
    scan_kernel<<<1, 256, 0, stream>>>(counts, cursor);
    scatter_kernel<<<NE/256, 256, 0, stream>>>(edge_index, cursor, order);

    egnn_edge_mfma<<<NE/16, 64, 0, stream>>>(
        x, edge_attr, edge_index, order, h_bf, WT_e1, WT_e2, WT_x1,
        b_e1, b_e2, W_g, b_g, b_x1, W_x2, agg, dxv);

    float* h_out = (float*)d_out;
    float* x_out = h_out + (size_t)NN*HID;

    egnn_node_mfma<<<NN/16, 64, 0, stream>>>(
        h, x, mask, h_bf, agg, dxv, WT_n1, b_n1, WT_n2, b_n2, h_out, x_out);
}